// Round 9
// baseline (409.905 us; speedup 1.0000x reference)
//
#include <hip/hip_runtime.h>
#include <hip/hip_bf16.h>

#define G_N 96
#define N_N 250
#define N_P 256
#define E_N 64
#define OUT_GSTRIDE (250 * 750)          // per-graph slab inside one output tensor (floats)
#define OUT_STRIDE  (96 * 250 * 750)     // 18,000,000 floats per output tensor

typedef __attribute__((ext_vector_type(4))) float floatx4;
typedef __attribute__((ext_vector_type(2))) float floatx2;
typedef __attribute__((ext_vector_type(8))) short shortx8;
typedef __attribute__((ext_vector_type(4))) short shortx4;

__device__ __forceinline__ float bf2f(unsigned short u) {
    union { unsigned int i; float f; } v; v.i = ((unsigned int)u) << 16; return v.f;
}
__device__ __forceinline__ unsigned short f2bf(float f) {
    union { float f; unsigned int i; } v; v.f = f;
    unsigned int x = v.i;
    return (unsigned short)((x + 0x7fffu + ((x >> 16) & 1u)) >> 16);  // RNE
}

// ---------------------------------------------------------------------------
// K1: nodevec = tanh(concat(hist,prior,obs) @ W + b)  -> bf16 [96][256][64]
// ---------------------------------------------------------------------------
__global__ __launch_bounds__(256) void k_embed(
    const float* __restrict__ hist, const float* __restrict__ prior,
    const float* __restrict__ obs, const float* __restrict__ Wemb,
    const float* __restrict__ bemb, unsigned short* __restrict__ nvb)
{
    __shared__ __attribute__((aligned(16))) float Xt[32][68];  // [k][n], pad 68
    __shared__ __attribute__((aligned(16))) float Wl[32][64];  // [k][e]
    const int t  = threadIdx.x;
    const int tx = t & 15, ty = t >> 4;
    const int rr0 = blockIdx.x * 64;   // padded row base; 64 | 256 so g uniform
    const int g   = rr0 >> 8;
    const int n0  = rr0 & 255;

    float acc[4][4] = {};

    for (int c = 0; c < 7; ++c) {      // 7 K-chunks of 32; source boundaries align
        const float* src; int rowlen, off;
        if (c < 4)      { src = hist;  rowlen = 128; off = c << 5; }
        else if (c < 6) { src = prior; rowlen = 64;  off = (c - 4) << 5; }
        else            { src = obs;   rowlen = 32;  off = 0; }
        __syncthreads();
        {   // stage X chunk transposed: 64 rows x 32 d
            const int d  = t & 31;
            const int nb = t >> 5;
            #pragma unroll
            for (int p = 0; p < 8; ++p) {
                const int nl = nb + p * 8;
                const int n  = n0 + nl;
                float v = 0.0f;
                if (n < N_N) v = src[(size_t)(g * N_N + n) * rowlen + off + d];
                Xt[d][nl] = v;
            }
        }
        {   // stage W chunk: 32 d x 64 e
            const int e  = t & 63;
            const int db = t >> 6;
            #pragma unroll
            for (int p = 0; p < 8; ++p) {
                const int dl = db + p * 4;
                Wl[dl][e] = Wemb[(c * 32 + dl) * 64 + e];
            }
        }
        __syncthreads();
        #pragma unroll
        for (int k = 0; k < 32; ++k) {
            const float4 av = *(const float4*)&Xt[k][4 * ty];
            const float4 bv = *(const float4*)&Wl[k][4 * tx];
            const float a[4] = {av.x, av.y, av.z, av.w};
            const float b[4] = {bv.x, bv.y, bv.z, bv.w};
            #pragma unroll
            for (int r = 0; r < 4; ++r)
                #pragma unroll
                for (int cc = 0; cc < 4; ++cc)
                    acc[r][cc] = fmaf(a[r], b[cc], acc[r][cc]);
        }
    }
    #pragma unroll
    for (int r = 0; r < 4; ++r) {
        const int nl = 4 * ty + r;
        const int n  = n0 + nl;
        unsigned short* d2 = nvb + ((size_t)g * N_P + (n0 + nl)) * E_N + 4 * tx;
        #pragma unroll
        for (int cc = 0; cc < 4; ++cc) {
            float v = 0.0f;
            if (n < N_N) v = tanhf(acc[r][cc] + bemb[4 * tx + cc]);
            d2[cc] = f2bf(v);
        }
    }
}

// ---------------------------------------------------------------------------
// K2a: S = relu(nv @ nv^T) per graph (bf16 MFMA 16x16x32, K=64) + fp32
// rowsums. Block owns 16 full rows (256 cols) -> rowsum needs no atomics.
// ---------------------------------------------------------------------------
__global__ __launch_bounds__(256) void k_sim(
    const unsigned short* __restrict__ nvb, unsigned short* __restrict__ Sb,
    float* __restrict__ rowsum)
{
    const int blk = blockIdx.x;          // 96*16
    const int g   = blk >> 4;
    const int i0  = (blk & 15) << 4;
    const int t    = threadIdx.x;
    const int w    = t >> 6;
    const int lane = t & 63;
    const int m = lane & 15, kg = lane >> 4;

    const shortx8* nvg = (const shortx8*)(nvb + (size_t)g * N_P * E_N);
    const shortx8 a0 = nvg[(i0 + m) * 8 + kg];       // k in [8kg, 8kg+8)
    const shortx8 a1 = nvg[(i0 + m) * 8 + 4 + kg];   // k in [32+8kg, ...)

    floatx4 acc[4];
    const floatx4 zero = {0.f, 0.f, 0.f, 0.f};
    #pragma unroll
    for (int tt = 0; tt < 4; ++tt) {
        const int j = (w << 6) + (tt << 4) + m;      // B-frag: n=lane&15, row-major nv
        const shortx8 b0 = nvg[j * 8 + kg];
        const shortx8 b1 = nvg[j * 8 + 4 + kg];
        floatx4 c = zero;
        c = __builtin_amdgcn_mfma_f32_16x16x32_bf16(a0, b0, c, 0, 0, 0);
        c = __builtin_amdgcn_mfma_f32_16x16x32_bf16(a1, b1, c, 0, 0, 0);
        acc[tt] = c;
    }

    float v[4] = {0.f, 0.f, 0.f, 0.f};
    unsigned short* Sg = Sb + (size_t)g * N_P * N_P;
    #pragma unroll
    for (int tt = 0; tt < 4; ++tt) {
        #pragma unroll
        for (int r = 0; r < 4; ++r) {
            float s = acc[tt][r];
            s = s > 0.f ? s : 0.f;                   // relu
            const int il = (kg << 2) + r;            // C/D: row=(lane>>4)*4+reg
            const int j  = (w << 6) + (tt << 4) + m; // col=lane&15
            Sg[(size_t)(i0 + il) * N_P + j] = f2bf(s);
            v[r] += s;
        }
    }
    #pragma unroll
    for (int r = 0; r < 4; ++r) {                    // reduce over m (16 lanes)
        v[r] += __shfl_xor(v[r], 1);
        v[r] += __shfl_xor(v[r], 2);
        v[r] += __shfl_xor(v[r], 4);
        v[r] += __shfl_xor(v[r], 8);
    }
    __shared__ float rs[4][16];
    if (m == 0) {
        #pragma unroll
        for (int r = 0; r < 4; ++r) rs[w][(kg << 2) + r] = v[r];
    }
    __syncthreads();
    if (t < 16) rowsum[g * N_P + i0 + t] = rs[0][t] + rs[1][t] + rs[2][t] + rs[3][t];
}

// ---------------------------------------------------------------------------
// K2b: t_i = sum_j S_ij d_j ; r=1/(d_i t_i+1e-9); c=r*d; w=c*d
// Wave-per-row, fully coalesced. 96*64 blocks.
// ---------------------------------------------------------------------------
__global__ __launch_bounds__(256) void k_trans(
    const unsigned short* __restrict__ Sb, const float* __restrict__ rowsum,
    float* __restrict__ cArr, float* __restrict__ wArr)
{
    const int blk = (blockIdx.x & 7) * 768 + (blockIdx.x >> 3);  // XCD swizzle, 6144 blocks
    const int g  = blk >> 6;
    const int r0 = (blk & 63) << 2;      // 4 rows per block, one per wave
    const int t = threadIdx.x;
    const int w = t >> 6, lane = t & 63;
    __shared__ __attribute__((aligned(16))) float dL[N_P];
    dL[t] = rsqrtf(rowsum[g * N_P + t] + 1e-9f);
    __syncthreads();
    const int row = r0 + w;
    const shortx4 sv = *(const shortx4*)(Sb + (size_t)g * N_P * N_P
                                         + (size_t)row * N_P + lane * 4);
    const float4 dv = *(const float4*)&dL[lane * 4];
    float a = bf2f((unsigned short)sv[0]) * dv.x
            + bf2f((unsigned short)sv[1]) * dv.y
            + bf2f((unsigned short)sv[2]) * dv.z
            + bf2f((unsigned short)sv[3]) * dv.w;
    #pragma unroll
    for (int s = 32; s; s >>= 1) a += __shfl_xor(a, s);
    if (lane == 0) {
        const float d = dL[row];
        const float r = 1.0f / (d * a + 1e-9f);
        const float c = r * d;
        cArr[g * N_P + row] = c;
        wArr[g * N_P + row] = c * d;
    }
}

// ---------------------------------------------------------------------------
// K3 v5: r5's staged compute (As/Bs -> MFMA -> pAll/qAll LDS, stride 260)
// + FILL-PATTERN write phase: per even row-pair, the 1500-float span per
// tensor is 6 wave-iterations of contiguous 16B-aligned float4 stores
// (1024B/wave-instr -- identical to the 6TB/s fillBuffer pattern). Each
// lane builds its quad from two conflict-free 8B ds_read_b64 (lanes at
// 16B stride); the x3 wrap and the 750-straddle fall out of per-half
// compare-subtract zone math. No sub-16B global stores anywhere.
// ---------------------------------------------------------------------------
__global__ __launch_bounds__(256) void k_pq(
    const unsigned short* __restrict__ Sb, const float* __restrict__ rowsum,
    const float* __restrict__ cArr, const float* __restrict__ wArr,
    float* __restrict__ out)
{
    const int blk = (blockIdx.x & 7) * 192 + (blockIdx.x >> 3);  // XCD swizzle, 1536 blocks
    const int g   = blk >> 4;
    const int i0  = (blk & 15) << 4;     // 16-row stripe
    const int t    = threadIdx.x;
    const int w    = t >> 6;
    const int lane = t & 63;
    const int m = lane & 15, kg = lane >> 4;

    __shared__ __attribute__((aligned(16))) unsigned short As[16][40];   // stripe rows x 32k
    __shared__ __attribute__((aligned(16))) unsigned short Bs[256][40];  // all rows x 32k
    __shared__ __attribute__((aligned(16))) float wL[N_P];
    __shared__ __attribute__((aligned(16))) float cC[N_P];
    __shared__ float dR16[16];
    __shared__ __attribute__((aligned(16))) float pAll[16][260];  // stride 260: even, 8B-safe
    __shared__ __attribute__((aligned(16))) float qAll[16][260];

    wL[t] = wArr[g * N_P + t];
    cC[t] = cArr[g * N_P + t];
    if (t < 16) dR16[t] = rsqrtf(rowsum[g * N_P + i0 + t] + 1e-9f);

    const unsigned short* Sg = Sb + (size_t)g * N_P * N_P;

    floatx4 acc[4];
    const floatx4 zero = {0.f, 0.f, 0.f, 0.f};
    #pragma unroll
    for (int tt = 0; tt < 4; ++tt) acc[tt] = zero;

    for (int kb = 0; kb < 8; ++kb) {
        __syncthreads();
        if (t < 64) {      // stage A chunk: 16 rows x 32 k (64 x uint4)
            const int row = t >> 2, c4 = t & 3;
            *(uint4*)&As[row][c4 * 8] =
                *(const uint4*)(Sg + (size_t)(i0 + row) * N_P + kb * 32 + c4 * 8);
        }
        #pragma unroll
        for (int q4 = 0; q4 < 4; ++q4) {   // stage B chunk: 256 rows x 32 k (1024 x uint4)
            const int u = t + (q4 << 8);
            const int row = u >> 2, c4 = u & 3;
            *(uint4*)&Bs[row][c4 * 8] =
                *(const uint4*)(Sg + (size_t)row * N_P + kb * 32 + c4 * 8);
        }
        __syncthreads();
        // build p slice for this k-chunk (cols kb*32..kb*32+31)
        #pragma unroll
        for (int q2 = 0; q2 < 2; ++q2) {
            const int idx = t + (q2 << 8);
            const int row = idx >> 5, kl = idx & 31;
            const int col = kb * 32 + kl;
            float pv = dR16[row] * bf2f(As[row][kl]) * cC[col];
            if (i0 + row == col) pv = 0.f;
            pAll[row][col] = pv;
        }
        // MFMA: A-frag (w folded), B-frags per wave column block
        const shortx8 a = *(const shortx8*)&As[m][kg << 3];
        const float4 w0 = *(const float4*)&wL[kb * 32 + (kg << 3)];
        const float4 w1 = *(const float4*)&wL[kb * 32 + (kg << 3) + 4];
        const float wv[8] = {w0.x, w0.y, w0.z, w0.w, w1.x, w1.y, w1.z, w1.w};
        shortx8 aw;
        #pragma unroll
        for (int u = 0; u < 8; ++u)
            aw[u] = (short)f2bf(bf2f((unsigned short)a[u]) * wv[u]);
        #pragma unroll
        for (int tt = 0; tt < 4; ++tt) {
            const shortx8 b = *(const shortx8*)&Bs[(w << 6) + (tt << 4) + m][kg << 3];
            acc[tt] = __builtin_amdgcn_mfma_f32_16x16x32_bf16(aw, b, acc[tt], 0, 0, 0);
        }
    }

    // q -> LDS (C/D layout: row = kg*4+r in stripe, col = w*64 + tt*16 + m)
    #pragma unroll
    for (int tt = 0; tt < 4; ++tt) {
        #pragma unroll
        for (int r = 0; r < 4; ++r) {
            const int lrow = (kg << 2) + r;
            const int col  = (w << 6) + (tt << 4) + m;
            float qv = acc[tt][r] * dR16[lrow] * cC[col];
            if (i0 + lrow == col) qv = 0.f;
            qAll[lrow][col] = qv;
        }
    }
    __syncthreads();

    // ---- write phase v5: 8 row-pairs; per pair a 1500-float span per
    // tensor, written as 6 wave-iterations of contiguous float4 stores.
    for (int pr = 0; pr < 8; ++pr) {
        const int i = i0 + (pr << 1);
        if (i >= N_N) break;                 // block-uniform; 250 even
        const float* pA = &pAll[(pr << 1)][0];
        const float* pB = &pAll[(pr << 1) + 1][0];
        const float* qA = &qAll[(pr << 1)][0];
        const float* qB = &qAll[(pr << 1) + 1][0];
        const size_t base = (size_t)g * OUT_GSTRIDE + (size_t)i * 750;
        #pragma unroll
        for (int u = 0; u < 6; ++u) {
            const int f0 = (u << 8) + (lane << 2);
            if (f0 < 1500) {                 // trims high lanes at u=5 only
                const int e1 = f0 + 2;
                const bool h0 = f0 >= 750, h1 = e1 >= 750;
                int c0 = h0 ? f0 - 750 : f0;
                int c1 = h1 ? e1 - 750 : e1;
                c0 = c0 >= 500 ? c0 - 500 : (c0 >= 250 ? c0 - 250 : c0);
                c1 = c1 >= 500 ? c1 - 500 : (c1 >= 250 ? c1 - 250 : c1);
                const floatx2 pl = *(const floatx2*)((h0 ? pB : pA) + c0);
                const floatx2 ph = *(const floatx2*)((h1 ? pB : pA) + c1);
                const floatx2 ql = *(const floatx2*)((h0 ? qB : qA) + c0);
                const floatx2 qh = *(const floatx2*)((h1 ? qB : qA) + c1);
                const floatx4 p4 = {pl[0], pl[1], ph[0], ph[1]};
                const floatx4 q4 = {ql[0], ql[1], qh[0], qh[1]};
                float* d0 = out + base + f0;
                *(floatx4*)(d0) = p4;
                *(floatx4*)(d0 + OUT_STRIDE) = q4;
                *(floatx4*)(d0 + 2 * (size_t)OUT_STRIDE) = p4;
                *(floatx4*)(d0 + 3 * (size_t)OUT_STRIDE) = q4;
            }
        }
    }
}

extern "C" void kernel_launch(void* const* d_in, const int* in_sizes, int n_in,
                              void* d_out, int out_size, void* d_ws, size_t ws_size,
                              hipStream_t stream) {
    const float* hist  = (const float*)d_in[0];
    const float* prior = (const float*)d_in[1];
    const float* obs   = (const float*)d_in[2];
    const float* Wemb  = (const float*)d_in[3];
    const float* bemb  = (const float*)d_in[4];
    float* out = (float*)d_out;

    char* p = (char*)d_ws;
    unsigned short* nvb = (unsigned short*)p; p += (size_t)G_N * N_P * E_N * 2;   // 3.1 MB
    unsigned short* Sb  = (unsigned short*)p; p += (size_t)G_N * N_P * N_P * 2;   // 12.6 MB
    float* rowsum = (float*)p; p += (size_t)G_N * N_P * 4;
    float* cArr   = (float*)p; p += (size_t)G_N * N_P * 4;
    float* wArr   = (float*)p; p += (size_t)G_N * N_P * 4;
    // total ~16 MB of ws

    k_embed<<<dim3(G_N * N_P / 64), dim3(256), 0, stream>>>(hist, prior, obs, Wemb, bemb, nvb);
    k_sim  <<<dim3(G_N * 16),       dim3(256), 0, stream>>>(nvb, Sb, rowsum);
    k_trans<<<dim3(G_N * 64),       dim3(256), 0, stream>>>(Sb, rowsum, cArr, wArr);
    k_pq   <<<dim3(G_N * 16),       dim3(256), 0, stream>>>(Sb, rowsum, cArr, wArr, out);
}

// Round 10
// 395.923 us; speedup vs baseline: 1.0353x; 1.0353x over previous
//
#include <hip/hip_runtime.h>
#include <hip/hip_bf16.h>

#define G_N 96
#define N_N 250
#define N_P 256
#define E_N 64
#define OUT_GSTRIDE (250 * 750)          // per-graph slab inside one output tensor (floats)
#define OUT_STRIDE  (96 * 250 * 750)     // 18,000,000 floats per output tensor

typedef __attribute__((ext_vector_type(4))) float floatx4;
typedef __attribute__((ext_vector_type(2))) float floatx2;
typedef __attribute__((ext_vector_type(8))) short shortx8;
typedef __attribute__((ext_vector_type(4))) short shortx4;

__device__ __forceinline__ float bf2f(unsigned short u) {
    union { unsigned int i; float f; } v; v.i = ((unsigned int)u) << 16; return v.f;
}
__device__ __forceinline__ unsigned short f2bf(float f) {
    union { float f; unsigned int i; } v; v.f = f;
    unsigned int x = v.i;
    return (unsigned short)((x + 0x7fffu + ((x >> 16) & 1u)) >> 16);  // RNE
}

// ---------------------------------------------------------------------------
// K1: nodevec = tanh(concat(hist,prior,obs) @ W + b)  -> bf16 [96][256][64]
// ---------------------------------------------------------------------------
__global__ __launch_bounds__(256) void k_embed(
    const float* __restrict__ hist, const float* __restrict__ prior,
    const float* __restrict__ obs, const float* __restrict__ Wemb,
    const float* __restrict__ bemb, unsigned short* __restrict__ nvb)
{
    __shared__ __attribute__((aligned(16))) float Xt[32][68];  // [k][n], pad 68
    __shared__ __attribute__((aligned(16))) float Wl[32][64];  // [k][e]
    const int t  = threadIdx.x;
    const int tx = t & 15, ty = t >> 4;
    const int rr0 = blockIdx.x * 64;   // padded row base; 64 | 256 so g uniform
    const int g   = rr0 >> 8;
    const int n0  = rr0 & 255;

    float acc[4][4] = {};

    for (int c = 0; c < 7; ++c) {      // 7 K-chunks of 32; source boundaries align
        const float* src; int rowlen, off;
        if (c < 4)      { src = hist;  rowlen = 128; off = c << 5; }
        else if (c < 6) { src = prior; rowlen = 64;  off = (c - 4) << 5; }
        else            { src = obs;   rowlen = 32;  off = 0; }
        __syncthreads();
        {   // stage X chunk transposed: 64 rows x 32 d
            const int d  = t & 31;
            const int nb = t >> 5;
            #pragma unroll
            for (int p = 0; p < 8; ++p) {
                const int nl = nb + p * 8;
                const int n  = n0 + nl;
                float v = 0.0f;
                if (n < N_N) v = src[(size_t)(g * N_N + n) * rowlen + off + d];
                Xt[d][nl] = v;
            }
        }
        {   // stage W chunk: 32 d x 64 e
            const int e  = t & 63;
            const int db = t >> 6;
            #pragma unroll
            for (int p = 0; p < 8; ++p) {
                const int dl = db + p * 4;
                Wl[dl][e] = Wemb[(c * 32 + dl) * 64 + e];
            }
        }
        __syncthreads();
        #pragma unroll
        for (int k = 0; k < 32; ++k) {
            const float4 av = *(const float4*)&Xt[k][4 * ty];
            const float4 bv = *(const float4*)&Wl[k][4 * tx];
            const float a[4] = {av.x, av.y, av.z, av.w};
            const float b[4] = {bv.x, bv.y, bv.z, bv.w};
            #pragma unroll
            for (int r = 0; r < 4; ++r)
                #pragma unroll
                for (int cc = 0; cc < 4; ++cc)
                    acc[r][cc] = fmaf(a[r], b[cc], acc[r][cc]);
        }
    }
    #pragma unroll
    for (int r = 0; r < 4; ++r) {
        const int nl = 4 * ty + r;
        const int n  = n0 + nl;
        unsigned short* d2 = nvb + ((size_t)g * N_P + (n0 + nl)) * E_N + 4 * tx;
        #pragma unroll
        for (int cc = 0; cc < 4; ++cc) {
            float v = 0.0f;
            if (n < N_N) v = tanhf(acc[r][cc] + bemb[4 * tx + cc]);
            d2[cc] = f2bf(v);
        }
    }
}

// ---------------------------------------------------------------------------
// K2a: S = relu(nv @ nv^T) per graph (bf16 MFMA 16x16x32, K=64) + fp32
// rowsums. Block owns 16 full rows (256 cols) -> rowsum needs no atomics.
// ---------------------------------------------------------------------------
__global__ __launch_bounds__(256) void k_sim(
    const unsigned short* __restrict__ nvb, unsigned short* __restrict__ Sb,
    float* __restrict__ rowsum)
{
    const int blk = blockIdx.x;          // 96*16
    const int g   = blk >> 4;
    const int i0  = (blk & 15) << 4;
    const int t    = threadIdx.x;
    const int w    = t >> 6;
    const int lane = t & 63;
    const int m = lane & 15, kg = lane >> 4;

    const shortx8* nvg = (const shortx8*)(nvb + (size_t)g * N_P * E_N);
    const shortx8 a0 = nvg[(i0 + m) * 8 + kg];       // k in [8kg, 8kg+8)
    const shortx8 a1 = nvg[(i0 + m) * 8 + 4 + kg];   // k in [32+8kg, ...)

    floatx4 acc[4];
    const floatx4 zero = {0.f, 0.f, 0.f, 0.f};
    #pragma unroll
    for (int tt = 0; tt < 4; ++tt) {
        const int j = (w << 6) + (tt << 4) + m;      // B-frag: n=lane&15, row-major nv
        const shortx8 b0 = nvg[j * 8 + kg];
        const shortx8 b1 = nvg[j * 8 + 4 + kg];
        floatx4 c = zero;
        c = __builtin_amdgcn_mfma_f32_16x16x32_bf16(a0, b0, c, 0, 0, 0);
        c = __builtin_amdgcn_mfma_f32_16x16x32_bf16(a1, b1, c, 0, 0, 0);
        acc[tt] = c;
    }

    float v[4] = {0.f, 0.f, 0.f, 0.f};
    unsigned short* Sg = Sb + (size_t)g * N_P * N_P;
    #pragma unroll
    for (int tt = 0; tt < 4; ++tt) {
        #pragma unroll
        for (int r = 0; r < 4; ++r) {
            float s = acc[tt][r];
            s = s > 0.f ? s : 0.f;                   // relu
            const int il = (kg << 2) + r;            // C/D: row=(lane>>4)*4+reg
            const int j  = (w << 6) + (tt << 4) + m; // col=lane&15
            Sg[(size_t)(i0 + il) * N_P + j] = f2bf(s);
            v[r] += s;
        }
    }
    #pragma unroll
    for (int r = 0; r < 4; ++r) {                    // reduce over m (16 lanes)
        v[r] += __shfl_xor(v[r], 1);
        v[r] += __shfl_xor(v[r], 2);
        v[r] += __shfl_xor(v[r], 4);
        v[r] += __shfl_xor(v[r], 8);
    }
    __shared__ float rs[4][16];
    if (m == 0) {
        #pragma unroll
        for (int r = 0; r < 4; ++r) rs[w][(kg << 2) + r] = v[r];
    }
    __syncthreads();
    if (t < 16) rowsum[g * N_P + i0 + t] = rs[0][t] + rs[1][t] + rs[2][t] + rs[3][t];
}

// ---------------------------------------------------------------------------
// K2b: t_i = sum_j S_ij d_j ; r=1/(d_i t_i+1e-9); c=r*d; w=c*d
// Wave-per-row, fully coalesced. 96*64 blocks.
// ---------------------------------------------------------------------------
__global__ __launch_bounds__(256) void k_trans(
    const unsigned short* __restrict__ Sb, const float* __restrict__ rowsum,
    float* __restrict__ cArr, float* __restrict__ wArr)
{
    const int blk = (blockIdx.x & 7) * 768 + (blockIdx.x >> 3);  // XCD swizzle, 6144 blocks
    const int g  = blk >> 6;
    const int r0 = (blk & 63) << 2;      // 4 rows per block, one per wave
    const int t = threadIdx.x;
    const int w = t >> 6, lane = t & 63;
    __shared__ __attribute__((aligned(16))) float dL[N_P];
    dL[t] = rsqrtf(rowsum[g * N_P + t] + 1e-9f);
    __syncthreads();
    const int row = r0 + w;
    const shortx4 sv = *(const shortx4*)(Sb + (size_t)g * N_P * N_P
                                         + (size_t)row * N_P + lane * 4);
    const float4 dv = *(const float4*)&dL[lane * 4];
    float a = bf2f((unsigned short)sv[0]) * dv.x
            + bf2f((unsigned short)sv[1]) * dv.y
            + bf2f((unsigned short)sv[2]) * dv.z
            + bf2f((unsigned short)sv[3]) * dv.w;
    #pragma unroll
    for (int s = 32; s; s >>= 1) a += __shfl_xor(a, s);
    if (lane == 0) {
        const float d = dL[row];
        const float r = 1.0f / (d * a + 1e-9f);
        const float c = r * d;
        cArr[g * N_P + row] = c;
        wArr[g * N_P + row] = c * d;
    }
}

// ---------------------------------------------------------------------------
// K3: M = (S*diag(w)) @ S^T per graph, Q = Dd M Dc masked -> compact Qb
// fp32 [96][256][256]. Fragment stores are 64B-aligned coalesced segments
// (row pitch 1024B). NO wide-pitch output stores here. (r2-verified.)
// ---------------------------------------------------------------------------
__global__ __launch_bounds__(256) void k_mm(
    const unsigned short* __restrict__ Sb, const float* __restrict__ rowsum,
    const float* __restrict__ cArr, const float* __restrict__ wArr,
    float* __restrict__ Qb)
{
    const int blk = (blockIdx.x & 7) * 192 + (blockIdx.x >> 3);  // XCD swizzle, 1536 blocks
    const int g   = blk >> 4;
    const int i0  = ((blk >> 2) & 3) << 6;
    const int j0  = (blk & 3) << 6;
    const int t    = threadIdx.x;
    const int w    = t >> 6;
    const int lane = t & 63;
    const int m = lane & 15, kg = lane >> 4;

    __shared__ __attribute__((aligned(16))) unsigned short As[64][40]; // 80B stride
    __shared__ __attribute__((aligned(16))) unsigned short Bs[64][40];
    __shared__ float dRow[64], cCol[64];
    __shared__ __attribute__((aligned(16))) float wL[N_P];

    if (t < 64) dRow[t] = rsqrtf(rowsum[g * N_P + i0 + t] + 1e-9f);
    else if (t < 128) cCol[t - 64] = cArr[g * N_P + j0 + (t - 64)];
    wL[t] = wArr[g * N_P + t];

    const unsigned short* Sg = Sb + (size_t)g * N_P * N_P;

    floatx4 acc[4];
    const floatx4 zero = {0.f, 0.f, 0.f, 0.f};
    #pragma unroll
    for (int tt = 0; tt < 4; ++tt) acc[tt] = zero;

    const int sr = t >> 2, sc = t & 3;   // staging: 16B per thread per matrix
    for (int kb = 0; kb < 8; ++kb) {
        __syncthreads();
        *(uint4*)&As[sr][sc * 8] = *(const uint4*)(Sg + (size_t)(i0 + sr) * N_P + kb * 32 + sc * 8);
        *(uint4*)&Bs[sr][sc * 8] = *(const uint4*)(Sg + (size_t)(j0 + sr) * N_P + kb * 32 + sc * 8);
        __syncthreads();
        const shortx8 a = *(const shortx8*)&As[(w << 4) + m][kg << 3];
        const float4 w0 = *(const float4*)&wL[kb * 32 + (kg << 3)];
        const float4 w1 = *(const float4*)&wL[kb * 32 + (kg << 3) + 4];
        const float wv[8] = {w0.x, w0.y, w0.z, w0.w, w1.x, w1.y, w1.z, w1.w};
        shortx8 aw;
        #pragma unroll
        for (int u = 0; u < 8; ++u)
            aw[u] = (short)f2bf(bf2f((unsigned short)a[u]) * wv[u]);
        #pragma unroll
        for (int tt = 0; tt < 4; ++tt) {
            const shortx8 b = *(const shortx8*)&Bs[(tt << 4) + m][kg << 3];
            acc[tt] = __builtin_amdgcn_mfma_f32_16x16x32_bf16(aw, b, acc[tt], 0, 0, 0);
        }
    }

    float dR[4], cC[4];
    #pragma unroll
    for (int r = 0; r < 4; ++r) dR[r] = dRow[(w << 4) + (kg << 2) + r];
    #pragma unroll
    for (int tt = 0; tt < 4; ++tt) cC[tt] = cCol[(tt << 4) + m];

    float* Qg = Qb + (size_t)g * N_P * N_P;
    #pragma unroll
    for (int tt = 0; tt < 4; ++tt) {
        #pragma unroll
        for (int r = 0; r < 4; ++r) {
            const int I = i0 + (w << 4) + (kg << 2) + r;
            const int J = j0 + (tt << 4) + m;
            const float q = (I == J) ? 0.f : acc[tt][r] * dR[r] * cC[tt];
            Qg[(size_t)I * N_P + J] = q;   // pad rows/cols >=250 written too (harmless)
        }
    }
}

// ---------------------------------------------------------------------------
// K4: PURE streaming writer -- the first clean one this session: plain
// (non-NT) float2 stores (r1/r2's writer was NT+scalar = the known-bad
// combo), no LDS, no barriers, coalesced loads, thousands of independent
// waves so stores issue from cycle one. Per row: shortx4 S + floatx4 Q +
// floatx4 c loads (L2-hot via matched g->XCD swizzle), p computed on the
// fly, 24 x 8B stores (every replica offset 8B-aligned for every parity).
// ---------------------------------------------------------------------------
__global__ __launch_bounds__(256) void k_wr(
    const unsigned short* __restrict__ Sb, const float* __restrict__ Qb,
    const float* __restrict__ rowsum, const float* __restrict__ cArr,
    float* __restrict__ out)
{
    const int blk = (blockIdx.x & 7) * 384 + (blockIdx.x >> 3);  // XCD swizzle, 3072 blocks
    const int g  = blk >> 5;
    const int i0 = (blk & 31) << 3;      // 8 rows per block, 2 per wave
    const int t  = threadIdx.x;
    const int w  = t >> 6, lane = t & 63;
    const int c0 = lane << 2;

    const unsigned short* Sg = Sb + (size_t)g * N_P * N_P;
    const float* Qg = Qb + (size_t)g * N_P * N_P;
    float* o0 = out + (size_t)g * OUT_GSTRIDE;
    float* o1 = o0 + (size_t)OUT_STRIDE;
    float* o2 = o0 + 2 * (size_t)OUT_STRIDE;
    float* o3 = o0 + 3 * (size_t)OUT_STRIDE;

    #pragma unroll
    for (int rr = 0; rr < 2; ++rr) {
        const int i = i0 + (w << 1) + rr;
        if (i >= N_N) continue;                    // wave-uniform
        if (c0 >= 252) continue;                   // lane 63 idle
        const float dI = rsqrtf(rowsum[g * N_P + i] + 1e-9f);
        const shortx4 sv = *(const shortx4*)(Sg + (size_t)i * N_P + c0);
        const floatx4 q4 = *(const floatx4*)(Qg + (size_t)i * N_P + c0);
        const floatx4 cc4 = *(const floatx4*)(cArr + g * N_P + c0);
        const float p0 = (i == c0)     ? 0.f : dI * bf2f((unsigned short)sv[0]) * cc4[0];
        const float p1 = (i == c0 + 1) ? 0.f : dI * bf2f((unsigned short)sv[1]) * cc4[1];
        const float p2 = (i == c0 + 2) ? 0.f : dI * bf2f((unsigned short)sv[2]) * cc4[2];
        const float p3 = (i == c0 + 3) ? 0.f : dI * bf2f((unsigned short)sv[3]) * cc4[3];
        const floatx2 pxy = {p0, p1}, pzw = {p2, p3};
        const floatx2 qxy = {q4[0], q4[1]}, qzw = {q4[2], q4[3]};
        float* b0 = o0 + (size_t)i * 750 + c0;
        float* b1 = o1 + (size_t)i * 750 + c0;
        float* b2 = o2 + (size_t)i * 750 + c0;
        float* b3 = o3 + (size_t)i * 750 + c0;
        #pragma unroll
        for (int rep = 0; rep < 3; ++rep) {
            const int o = rep * 250;
            *(floatx2*)(b0 + o) = pxy;
            *(floatx2*)(b1 + o) = qxy;
            *(floatx2*)(b2 + o) = pxy;
            *(floatx2*)(b3 + o) = qxy;
            if (lane < 62) {                       // zw cols valid (<=247)
                *(floatx2*)(b0 + o + 2) = pzw;
                *(floatx2*)(b1 + o + 2) = qzw;
                *(floatx2*)(b2 + o + 2) = pzw;
                *(floatx2*)(b3 + o + 2) = qzw;
            }
        }
    }
}

extern "C" void kernel_launch(void* const* d_in, const int* in_sizes, int n_in,
                              void* d_out, int out_size, void* d_ws, size_t ws_size,
                              hipStream_t stream) {
    const float* hist  = (const float*)d_in[0];
    const float* prior = (const float*)d_in[1];
    const float* obs   = (const float*)d_in[2];
    const float* Wemb  = (const float*)d_in[3];
    const float* bemb  = (const float*)d_in[4];
    float* out = (float*)d_out;

    char* p = (char*)d_ws;
    unsigned short* nvb = (unsigned short*)p; p += (size_t)G_N * N_P * E_N * 2;   // 3.1 MB
    unsigned short* Sb  = (unsigned short*)p; p += (size_t)G_N * N_P * N_P * 2;   // 12.6 MB
    float* rowsum = (float*)p; p += (size_t)G_N * N_P * 4;
    float* cArr   = (float*)p; p += (size_t)G_N * N_P * 4;
    float* wArr   = (float*)p; p += (size_t)G_N * N_P * 4;
    float* Qb     = (float*)p; p += (size_t)G_N * N_P * N_P * 4;                  // 25.2 MB
    // total ~41.5 MB of ws (fits: r2 used the same)

    k_embed<<<dim3(G_N * N_P / 64), dim3(256), 0, stream>>>(hist, prior, obs, Wemb, bemb, nvb);
    k_sim  <<<dim3(G_N * 16),       dim3(256), 0, stream>>>(nvb, Sb, rowsum);
    k_trans<<<dim3(G_N * 64),       dim3(256), 0, stream>>>(Sb, rowsum, cArr, wArr);
    k_mm   <<<dim3(G_N * 16),       dim3(256), 0, stream>>>(Sb, rowsum, cArr, wArr, Qb);
    k_wr   <<<dim3(G_N * 32),       dim3(256), 0, stream>>>(Sb, Qb, rowsum, cArr, out);
}

// Round 11
// 363.092 us; speedup vs baseline: 1.1289x; 1.0904x over previous
//
#include <hip/hip_runtime.h>
#include <hip/hip_bf16.h>

#define G_N 96
#define N_N 250
#define N_P 256
#define E_N 64
#define OUT_GSTRIDE (250 * 750)          // per-graph slab inside one output tensor (floats)
#define OUT_STRIDE  (96 * 250 * 750)     // 18,000,000 floats per output tensor

typedef __attribute__((ext_vector_type(4))) float floatx4;
typedef __attribute__((ext_vector_type(2))) float floatx2;
typedef __attribute__((ext_vector_type(8))) short shortx8;
typedef __attribute__((ext_vector_type(4))) short shortx4;

__device__ __forceinline__ float bf2f(unsigned short u) {
    union { unsigned int i; float f; } v; v.i = ((unsigned int)u) << 16; return v.f;
}
__device__ __forceinline__ unsigned short f2bf(float f) {
    union { float f; unsigned int i; } v; v.f = f;
    unsigned int x = v.i;
    return (unsigned short)((x + 0x7fffu + ((x >> 16) & 1u)) >> 16);  // RNE
}

// ---------------------------------------------------------------------------
// K1: nodevec = tanh(concat(hist,prior,obs) @ W + b)  -> bf16 [96][256][64]
// XCD swizzle: graph g's blocks land on XCD g/12 (same family as consumers).
// ---------------------------------------------------------------------------
__global__ __launch_bounds__(256) void k_embed(
    const float* __restrict__ hist, const float* __restrict__ prior,
    const float* __restrict__ obs, const float* __restrict__ Wemb,
    const float* __restrict__ bemb, unsigned short* __restrict__ nvb)
{
    __shared__ __attribute__((aligned(16))) float Xt[32][68];  // [k][n], pad 68
    __shared__ __attribute__((aligned(16))) float Wl[32][64];  // [k][e]
    const int t  = threadIdx.x;
    const int tx = t & 15, ty = t >> 4;
    const int b   = (blockIdx.x & 7) * 48 + (blockIdx.x >> 3);  // 384 = 8*48, bijective
    const int rr0 = b * 64;            // padded row base; 64 | 256 so g uniform
    const int g   = rr0 >> 8;
    const int n0  = rr0 & 255;

    float acc[4][4] = {};

    for (int c = 0; c < 7; ++c) {      // 7 K-chunks of 32; source boundaries align
        const float* src; int rowlen, off;
        if (c < 4)      { src = hist;  rowlen = 128; off = c << 5; }
        else if (c < 6) { src = prior; rowlen = 64;  off = (c - 4) << 5; }
        else            { src = obs;   rowlen = 32;  off = 0; }
        __syncthreads();
        {   // stage X chunk transposed: 64 rows x 32 d
            const int d  = t & 31;
            const int nb = t >> 5;
            #pragma unroll
            for (int p = 0; p < 8; ++p) {
                const int nl = nb + p * 8;
                const int n  = n0 + nl;
                float v = 0.0f;
                if (n < N_N) v = src[(size_t)(g * N_N + n) * rowlen + off + d];
                Xt[d][nl] = v;
            }
        }
        {   // stage W chunk: 32 d x 64 e
            const int e  = t & 63;
            const int db = t >> 6;
            #pragma unroll
            for (int p = 0; p < 8; ++p) {
                const int dl = db + p * 4;
                Wl[dl][e] = Wemb[(c * 32 + dl) * 64 + e];
            }
        }
        __syncthreads();
        #pragma unroll
        for (int k = 0; k < 32; ++k) {
            const float4 av = *(const float4*)&Xt[k][4 * ty];
            const float4 bv = *(const float4*)&Wl[k][4 * tx];
            const float a[4] = {av.x, av.y, av.z, av.w};
            const float b2[4] = {bv.x, bv.y, bv.z, bv.w};
            #pragma unroll
            for (int r = 0; r < 4; ++r)
                #pragma unroll
                for (int cc = 0; cc < 4; ++cc)
                    acc[r][cc] = fmaf(a[r], b2[cc], acc[r][cc]);
        }
    }
    #pragma unroll
    for (int r = 0; r < 4; ++r) {
        const int nl = 4 * ty + r;
        const int n  = n0 + nl;
        unsigned short* d2 = nvb + ((size_t)g * N_P + (n0 + nl)) * E_N + 4 * tx;
        #pragma unroll
        for (int cc = 0; cc < 4; ++cc) {
            float v = 0.0f;
            if (n < N_N) v = tanhf(acc[r][cc] + bemb[4 * tx + cc]);
            d2[cc] = f2bf(v);
        }
    }
}

// ---------------------------------------------------------------------------
// K2a: S = relu(nv @ nv^T) per graph (bf16 MFMA 16x16x32, K=64) + fp32
// rowsums. XCD swizzle matches k_pq: S lines are written into the L2 of
// the XCD that will re-read them (graph g <-> XCD g/12).
// ---------------------------------------------------------------------------
__global__ __launch_bounds__(256) void k_sim(
    const unsigned short* __restrict__ nvb, unsigned short* __restrict__ Sb,
    float* __restrict__ rowsum)
{
    const int blk = (blockIdx.x & 7) * 192 + (blockIdx.x >> 3);  // 1536 = 8*192
    const int g   = blk >> 4;
    const int i0  = (blk & 15) << 4;
    const int t    = threadIdx.x;
    const int w    = t >> 6;
    const int lane = t & 63;
    const int m = lane & 15, kg = lane >> 4;

    const shortx8* nvg = (const shortx8*)(nvb + (size_t)g * N_P * E_N);
    const shortx8 a0 = nvg[(i0 + m) * 8 + kg];       // k in [8kg, 8kg+8)
    const shortx8 a1 = nvg[(i0 + m) * 8 + 4 + kg];   // k in [32+8kg, ...)

    floatx4 acc[4];
    const floatx4 zero = {0.f, 0.f, 0.f, 0.f};
    #pragma unroll
    for (int tt = 0; tt < 4; ++tt) {
        const int j = (w << 6) + (tt << 4) + m;      // B-frag: n=lane&15, row-major nv
        const shortx8 b0 = nvg[j * 8 + kg];
        const shortx8 b1 = nvg[j * 8 + 4 + kg];
        floatx4 c = zero;
        c = __builtin_amdgcn_mfma_f32_16x16x32_bf16(a0, b0, c, 0, 0, 0);
        c = __builtin_amdgcn_mfma_f32_16x16x32_bf16(a1, b1, c, 0, 0, 0);
        acc[tt] = c;
    }

    float v[4] = {0.f, 0.f, 0.f, 0.f};
    unsigned short* Sg = Sb + (size_t)g * N_P * N_P;
    #pragma unroll
    for (int tt = 0; tt < 4; ++tt) {
        #pragma unroll
        for (int r = 0; r < 4; ++r) {
            float s = acc[tt][r];
            s = s > 0.f ? s : 0.f;                   // relu
            const int il = (kg << 2) + r;            // C/D: row=(lane>>4)*4+reg
            const int j  = (w << 6) + (tt << 4) + m; // col=lane&15
            Sg[(size_t)(i0 + il) * N_P + j] = f2bf(s);
            v[r] += s;
        }
    }
    #pragma unroll
    for (int r = 0; r < 4; ++r) {                    // reduce over m (16 lanes)
        v[r] += __shfl_xor(v[r], 1);
        v[r] += __shfl_xor(v[r], 2);
        v[r] += __shfl_xor(v[r], 4);
        v[r] += __shfl_xor(v[r], 8);
    }
    __shared__ float rs[4][16];
    if (m == 0) {
        #pragma unroll
        for (int r = 0; r < 4; ++r) rs[w][(kg << 2) + r] = v[r];
    }
    __syncthreads();
    if (t < 16) rowsum[g * N_P + i0 + t] = rs[0][t] + rs[1][t] + rs[2][t] + rs[3][t];
}

// ---------------------------------------------------------------------------
// K2b: t_i = sum_j S_ij d_j ; r=1/(d_i t_i+1e-9); c=r*d; w=c*d
// Wave-per-row, fully coalesced. 96*64 blocks.
// ---------------------------------------------------------------------------
__global__ __launch_bounds__(256) void k_trans(
    const unsigned short* __restrict__ Sb, const float* __restrict__ rowsum,
    float* __restrict__ cArr, float* __restrict__ wArr)
{
    const int blk = (blockIdx.x & 7) * 768 + (blockIdx.x >> 3);  // XCD swizzle, 6144 blocks
    const int g  = blk >> 6;
    const int r0 = (blk & 63) << 2;      // 4 rows per block, one per wave
    const int t = threadIdx.x;
    const int w = t >> 6, lane = t & 63;
    __shared__ __attribute__((aligned(16))) float dL[N_P];
    dL[t] = rsqrtf(rowsum[g * N_P + t] + 1e-9f);
    __syncthreads();
    const int row = r0 + w;
    const shortx4 sv = *(const shortx4*)(Sb + (size_t)g * N_P * N_P
                                         + (size_t)row * N_P + lane * 4);
    const float4 dv = *(const float4*)&dL[lane * 4];
    float a = bf2f((unsigned short)sv[0]) * dv.x
            + bf2f((unsigned short)sv[1]) * dv.y
            + bf2f((unsigned short)sv[2]) * dv.z
            + bf2f((unsigned short)sv[3]) * dv.w;
    #pragma unroll
    for (int s = 32; s; s >>= 1) a += __shfl_xor(a, s);
    if (lane == 0) {
        const float d = dL[row];
        const float r = 1.0f / (d * a + 1e-9f);
        const float c = r * d;
        cArr[g * N_P + row] = c;
        wArr[g * N_P + row] = c * d;
    }
}

// ---------------------------------------------------------------------------
// K3 v7: r6's fused structure + phase overlap.
//  - LDS 39.6 KB (pAll dropped; p recomputed from global S-row read, the
//    r7/r10-verified path) -> 4 blocks/CU (was 2).
//  - Phase stagger by (blk&1): odd blocks [write-p -> compute -> write-q],
//    even blocks [compute -> write-q -> write-p]. p needs no MFMA, so at
//    any instant ~half the resident blocks stream stores while the other
//    half compute -- breaking the lockstep that made compute and write
//    phases serialize chip-wide.
//  - write paths are r6's proven forms: q via qAll (conflict-free b128
//    reads, float2 stores), p via coalesced shortx4 S + float2 stores.
// ---------------------------------------------------------------------------
__global__ __launch_bounds__(256) void k_pq(
    const unsigned short* __restrict__ Sb, const float* __restrict__ rowsum,
    const float* __restrict__ cArr, const float* __restrict__ wArr,
    float* __restrict__ out)
{
    const int blk = (blockIdx.x & 7) * 192 + (blockIdx.x >> 3);  // XCD swizzle, 1536 blocks
    const int g   = blk >> 4;
    const int i0  = (blk & 15) << 4;     // 16-row stripe
    const int t    = threadIdx.x;
    const int w    = t >> 6;
    const int lane = t & 63;
    const int m = lane & 15, kg = lane >> 4;

    __shared__ __attribute__((aligned(16))) unsigned short As[16][40];   // stripe rows x 32k
    __shared__ __attribute__((aligned(16))) unsigned short Bs[256][40];  // all rows x 32k
    __shared__ __attribute__((aligned(16))) float wL[N_P];
    __shared__ __attribute__((aligned(16))) float cC[N_P];
    __shared__ float dR16[16];
    __shared__ __attribute__((aligned(16))) float qAll[16][260];  // 1040B row stride

    wL[t] = wArr[g * N_P + t];
    cC[t] = cArr[g * N_P + t];
    if (t < 16) dR16[t] = rsqrtf(rowsum[g * N_P + i0 + t] + 1e-9f);
    __syncthreads();

    const unsigned short* Sg = Sb + (size_t)g * N_P * N_P;
    float* o0 = out + (size_t)g * OUT_GSTRIDE;
    float* o1 = o0 + (size_t)OUT_STRIDE;
    float* o2 = o0 + 2 * (size_t)OUT_STRIDE;
    float* o3 = o0 + 3 * (size_t)OUT_STRIDE;
    const int c0 = lane << 2;

    auto writeP = [&]() {
        if (c0 >= 252) return;                     // lane 63 idle; no barriers inside
        #pragma unroll
        for (int rr = 0; rr < 4; ++rr) {
            const int row = (rr << 2) + w;
            const int i   = i0 + row;
            if (i >= N_N) continue;                // wave-uniform
            const float dI = dR16[row];
            const shortx4 sv = *(const shortx4*)(Sg + (size_t)i * N_P + c0);
            const float4 cc4 = *(const float4*)&cC[c0];
            const float p0 = (i == c0)     ? 0.f : dI * bf2f((unsigned short)sv[0]) * cc4.x;
            const float p1 = (i == c0 + 1) ? 0.f : dI * bf2f((unsigned short)sv[1]) * cc4.y;
            const float p2 = (i == c0 + 2) ? 0.f : dI * bf2f((unsigned short)sv[2]) * cc4.z;
            const float p3 = (i == c0 + 3) ? 0.f : dI * bf2f((unsigned short)sv[3]) * cc4.w;
            const floatx2 pxy = {p0, p1}, pzw = {p2, p3};
            float* b0 = o0 + (size_t)i * 750 + c0;
            float* b2 = o2 + (size_t)i * 750 + c0;
            #pragma unroll
            for (int rep = 0; rep < 3; ++rep) {
                const int o = rep * 250;
                *(floatx2*)(b0 + o) = pxy;
                *(floatx2*)(b2 + o) = pxy;
                if (lane < 62) {                   // zw cols valid (<=247)
                    *(floatx2*)(b0 + o + 2) = pzw;
                    *(floatx2*)(b2 + o + 2) = pzw;
                }
            }
        }
    };

    const bool pfirst = (blk & 1) != 0;
    if (pfirst) writeP();

    floatx4 acc[4];
    const floatx4 zero = {0.f, 0.f, 0.f, 0.f};
    #pragma unroll
    for (int tt = 0; tt < 4; ++tt) acc[tt] = zero;

    for (int kb = 0; kb < 8; ++kb) {
        __syncthreads();
        if (t < 64) {      // stage A chunk: 16 rows x 32 k (64 x uint4)
            const int row = t >> 2, c4 = t & 3;
            *(uint4*)&As[row][c4 * 8] =
                *(const uint4*)(Sg + (size_t)(i0 + row) * N_P + kb * 32 + c4 * 8);
        }
        #pragma unroll
        for (int q4 = 0; q4 < 4; ++q4) {   // stage B chunk: 256 rows x 32 k (1024 x uint4)
            const int u = t + (q4 << 8);
            const int row = u >> 2, c4 = u & 3;
            *(uint4*)&Bs[row][c4 * 8] =
                *(const uint4*)(Sg + (size_t)row * N_P + kb * 32 + c4 * 8);
        }
        __syncthreads();
        // MFMA: A-frag (w folded), B-frags per wave column block
        const shortx8 a = *(const shortx8*)&As[m][kg << 3];
        const float4 w0 = *(const float4*)&wL[kb * 32 + (kg << 3)];
        const float4 w1 = *(const float4*)&wL[kb * 32 + (kg << 3) + 4];
        const float wv[8] = {w0.x, w0.y, w0.z, w0.w, w1.x, w1.y, w1.z, w1.w};
        shortx8 aw;
        #pragma unroll
        for (int u = 0; u < 8; ++u)
            aw[u] = (short)f2bf(bf2f((unsigned short)a[u]) * wv[u]);
        #pragma unroll
        for (int tt = 0; tt < 4; ++tt) {
            const shortx8 b = *(const shortx8*)&Bs[(w << 6) + (tt << 4) + m][kg << 3];
            acc[tt] = __builtin_amdgcn_mfma_f32_16x16x32_bf16(aw, b, acc[tt], 0, 0, 0);
        }
    }

    // q -> LDS (C/D layout: row = kg*4+r in stripe, col = w*64 + tt*16 + m)
    #pragma unroll
    for (int tt = 0; tt < 4; ++tt) {
        #pragma unroll
        for (int r = 0; r < 4; ++r) {
            const int lrow = (kg << 2) + r;
            const int col  = (w << 6) + (tt << 4) + m;
            float qv = acc[tt][r] * dR16[lrow] * cC[col];
            if (i0 + lrow == col) qv = 0.f;
            qAll[lrow][col] = qv;
        }
    }
    __syncthreads();

    // write q: wave w owns rows {w, w+4, w+8, w+12}; lane L cols 4L..4L+3
    #pragma unroll
    for (int rr = 0; rr < 4; ++rr) {
        const int row = (rr << 2) + w;
        const int i   = i0 + row;
        if (i >= N_N) continue;                    // wave-uniform
        const floatx4 q4 = *(const floatx4*)&qAll[row][c0];  // c0<=252, +3 < 260
        if (c0 >= 252) continue;                   // lane 63 idle
        const floatx2 qxy = {q4[0], q4[1]}, qzw = {q4[2], q4[3]};
        float* b1 = o1 + (size_t)i * 750 + c0;
        float* b3 = o3 + (size_t)i * 750 + c0;
        #pragma unroll
        for (int rep = 0; rep < 3; ++rep) {
            const int o = rep * 250;
            *(floatx2*)(b1 + o) = qxy;
            *(floatx2*)(b3 + o) = qxy;
            if (lane < 62) {
                *(floatx2*)(b1 + o + 2) = qzw;
                *(floatx2*)(b3 + o + 2) = qzw;
            }
        }
    }

    if (!pfirst) writeP();
}

extern "C" void kernel_launch(void* const* d_in, const int* in_sizes, int n_in,
                              void* d_out, int out_size, void* d_ws, size_t ws_size,
                              hipStream_t stream) {
    const float* hist  = (const float*)d_in[0];
    const float* prior = (const float*)d_in[1];
    const float* obs   = (const float*)d_in[2];
    const float* Wemb  = (const float*)d_in[3];
    const float* bemb  = (const float*)d_in[4];
    float* out = (float*)d_out;

    char* p = (char*)d_ws;
    unsigned short* nvb = (unsigned short*)p; p += (size_t)G_N * N_P * E_N * 2;   // 3.1 MB
    unsigned short* Sb  = (unsigned short*)p; p += (size_t)G_N * N_P * N_P * 2;   // 12.6 MB
    float* rowsum = (float*)p; p += (size_t)G_N * N_P * 4;
    float* cArr   = (float*)p; p += (size_t)G_N * N_P * 4;
    float* wArr   = (float*)p; p += (size_t)G_N * N_P * 4;
    // total ~16 MB of ws

    k_embed<<<dim3(G_N * N_P / 64), dim3(256), 0, stream>>>(hist, prior, obs, Wemb, bemb, nvb);
    k_sim  <<<dim3(G_N * 16),       dim3(256), 0, stream>>>(nvb, Sb, rowsum);
    k_trans<<<dim3(G_N * 64),       dim3(256), 0, stream>>>(Sb, rowsum, cArr, wArr);
    k_pq   <<<dim3(G_N * 16),       dim3(256), 0, stream>>>(Sb, rowsum, cArr, wArr, out);
}